// Round 19
// baseline (220.213 us; speedup 1.0000x reference)
//
#include <hip/hip_runtime.h>
#include <math.h>

#define NS 256
#define BS 7
#define UU 8
#define NR 4
#define NT 8
#define DD 2
#define HID 200
#define CIN 32
#define PP 100.0f
#define NOISEF 1e-7f

typedef _Float16 f16x8 __attribute__((ext_vector_type(8)));
typedef float f32x4 __attribute__((ext_vector_type(4)));

#define AST 424      // activation buffer row stride (halves)
#define AST0 104     // layer-1 input stride (halves)
#define NTILES 28
#define B1_KC 3
#define B23_KC 13
#define B1_HALVES (B1_KC*NTILES*64*8)
#define B23_HALVES (B23_KC*NTILES*64*8)
#define BITER_HALVES (B1_HALVES + 2*B23_HALVES)
#define MROWS 32     // rows per k_mlp block

// ---------------- 4x4 complex Hermitian PD solve, 2 RHS (Cholesky) ----------------
__device__ void chol_solve(const float2 (*A)[NR], const float2 (*B)[DD], float2 (*X)[DD]) {
  float2 L[NR][NR];
  for (int j = 0; j < NR; ++j) {
    float d = A[j][j].x;
    for (int k = 0; k < j; ++k) d -= L[j][k].x * L[j][k].x + L[j][k].y * L[j][k].y;
    float ld = sqrtf(fmaxf(d, 1e-30f));
    L[j][j] = make_float2(ld, 0.f);
    float inv = 1.f / ld;
    for (int i = j + 1; i < NR; ++i) {
      float sr = A[i][j].x, si = A[i][j].y;
      for (int k = 0; k < j; ++k) {
        float2 a = L[i][k], b = L[j][k];
        sr -= a.x * b.x + a.y * b.y;
        si -= a.y * b.x - a.x * b.y;
      }
      L[i][j] = make_float2(sr * inv, si * inv);
    }
  }
  for (int c = 0; c < DD; ++c) {
    float2 z[NR];
    for (int i = 0; i < NR; ++i) {
      float sr = B[i][c].x, si = B[i][c].y;
      for (int k = 0; k < i; ++k) {
        float2 a = L[i][k], zz = z[k];
        sr -= a.x * zz.x - a.y * zz.y;
        si -= a.x * zz.y + a.y * zz.x;
      }
      float inv = 1.f / L[i][i].x;
      z[i] = make_float2(sr * inv, si * inv);
    }
    for (int i = NR - 1; i >= 0; --i) {
      float sr = z[i].x, si = z[i].y;
      for (int k = i + 1; k < NR; ++k) {
        float2 a = L[k][i], xx = X[k][c];
        sr -= a.x * xx.x + a.y * xx.y;
        si -= a.x * xx.y - a.y * xx.x;
      }
      float inv = 1.f / L[i][i].x;
      X[i][c] = make_float2(sr * inv, si * inv);
    }
  }
}

// ---------------- K0: initial power normalization ----------------
__global__ void k_norm0(const float* __restrict__ Vre, const float* __restrict__ Vim,
                        float2* __restrict__ Vcur) {
  int nl = blockIdx.x;
  int tid = threadIdx.x;
  size_t base = (size_t)nl * 128;
  float re = Vre[base + tid], im = Vim[base + tid];
  float p = re * re + im * im;
  p += __shfl_down(p, 32); p += __shfl_down(p, 16); p += __shfl_down(p, 8);
  p += __shfl_down(p, 4);  p += __shfl_down(p, 2);  p += __shfl_down(p, 1);
  __shared__ float sred[2];
  if ((tid & 63) == 0) sred[tid >> 6] = p;
  __syncthreads();
  float fro = sred[0] + sred[1];
  float sc = sqrtf(PP / fro);
  Vcur[base + tid] = make_float2(re * sc, im * sc);
}

// ---------------- k_s1n v3: 4 blocks per n (l mod 4 split) -> 4 blocks/CU ----------
// 512 threads = 8 waves. Compute: wave=k, lane=(i,c). Block p handles l = p, p+4.
__global__ __launch_bounds__(512, 2) void k_s1n(const float* __restrict__ Hre,
    const float* __restrict__ Him, const float2* __restrict__ Vcur,
    float2* __restrict__ Yb, float2* __restrict__ IGb) {
  int blk = blockIdx.x;
  int p = blk & 3, n = blk >> 2;
  int tid = threadIdx.x;
  int wave = tid >> 6;
  int lane = tid & 63;
  int i = lane >> 3, c = lane & 7;

  __shared__ float2 Vs[952];        // (k*8+j)*17 + t*2+d
  __shared__ float2 Cs[7][76];      // [k] c*9 + t
  __shared__ float2 Hl[7][268];     // [k] i*33 + r*8 + t
  __shared__ float2 Gk[7][8][10];
  __shared__ float2 Gs[16][10];     // [lc*8+i], lc = l>>2
  __shared__ float2 TdL[16][10];
  __shared__ float2 HV2L[16][8];

  const float2* Vn = Vcur + (size_t)n * 896;
  for (int idx = tid; idx < 896; idx += 512)
    Vs[(idx >> 4) * 17 + (idx & 15)] = Vn[idx];
  __syncthreads();

  if (tid < 448) {
    int k = tid >> 6, e = tid & 63, cc = e >> 3, t = e & 7;
    float sr = 0.f, si = 0.f;
    #pragma unroll
    for (int j = 0; j < 8; ++j) {
      const float2* vr = &Vs[(k * 8 + j) * 17];
      #pragma unroll
      for (int d = 0; d < 2; ++d) {
        float2 a = vr[t * 2 + d], b = vr[cc * 2 + d];
        sr += a.x * b.x + a.y * b.y;
        si += a.y * b.x - a.x * b.y;
      }
    }
    Cs[k][cc * 9 + t] = make_float2(sr, si);
  }

  for (int l = p; l < BS; l += 4) {
    int lc = l >> 2;
    __syncthreads();
    if (tid < 448) {
      int k = tid >> 6;
      int e4 = (tid & 63) * 4;
      size_t hbase = (((size_t)(n * 7 + k) * 7) + l) * 256 + e4;
      float4 re = *(const float4*)(Hre + hbase);
      float4 im = *(const float4*)(Him + hbase);
      int ii = e4 >> 5, rem = e4 & 31;
      float2* hp = &Hl[k][ii * 33 + rem];
      hp[0] = make_float2(re.x, im.x);
      hp[1] = make_float2(re.y, im.y);
      hp[2] = make_float2(re.z, im.z);
      hp[3] = make_float2(re.w, im.w);
    }
    __syncthreads();

    if (wave < 7) {
      int k = wave;
      const float2* hme = &Hl[k][i * 33];
      const float2* cme = &Cs[k][c * 9];
      float2 T[4];
      #pragma unroll
      for (int r = 0; r < 4; ++r) {
        float tr = 0.f, ti = 0.f;
        #pragma unroll
        for (int t = 0; t < 8; ++t) {
          float2 h = hme[r * 8 + t], cv = cme[t];
          tr += h.x * cv.x - h.y * cv.y;
          ti += h.x * cv.y + h.y * cv.x;
        }
        T[r] = make_float2(tr, ti);
      }
      float2 hb[4];
      #pragma unroll
      for (int s = 0; s < 4; ++s) hb[s] = hme[s * 8 + c];
      float2 G[10];
      {
        int ui = 0;
        #pragma unroll
        for (int r = 0; r < 4; ++r)
          #pragma unroll
          for (int s = r; s < 4; ++s) {
            G[ui].x = T[r].x * hb[s].x + T[r].y * hb[s].y;
            G[ui].y = T[r].y * hb[s].x - T[r].x * hb[s].y;
            ++ui;
          }
      }
      #pragma unroll
      for (int m = 1; m < 8; m <<= 1) {
        #pragma unroll
        for (int q = 0; q < 10; ++q) {
          G[q].x += __shfl_xor(G[q].x, m);
          G[q].y += __shfl_xor(G[q].y, m);
        }
      }
      if (c == 0) {
        #pragma unroll
        for (int q = 0; q < 10; ++q) Gk[k][i][q] = G[q];
      }

      if (k == l) {
        int r = c >> 1, d = c & 1;
        float hvx = 0.f, hvy = 0.f;
        const float2* vp = &Vs[(l * 8 + i) * 17 + d];
        #pragma unroll
        for (int t = 0; t < 8; ++t) {
          float2 h = hme[r * 8 + t], v = vp[t * 2];
          hvx += h.x * v.x - h.y * v.y;
          hvy += h.x * v.y + h.y * v.x;
        }
        float gx[8], gy[8];
        int base = lane & 56;
        #pragma unroll
        for (int pp = 0; pp < 8; ++pp) {
          gx[pp] = __shfl(hvx, base + pp);
          gy[pp] = __shfl(hvy, base + pp);
        }
        if (c == 0) {
          int ui = 0;
          #pragma unroll
          for (int r2 = 0; r2 < 4; ++r2)
            #pragma unroll
            for (int s2 = r2; s2 < 4; ++s2) {
              float tr = 0.f, ti = 0.f;
              #pragma unroll
              for (int d2 = 0; d2 < 2; ++d2) {
                float ax = gx[r2 * 2 + d2], ay = gy[r2 * 2 + d2];
                float bx = gx[s2 * 2 + d2], by = gy[s2 * 2 + d2];
                tr += ax * bx + ay * by;
                ti += ay * bx - ax * by;
              }
              TdL[lc * 8 + i][ui] = make_float2(tr, ti);
              ++ui;
            }
          #pragma unroll
          for (int x = 0; x < 8; ++x)
            HV2L[lc * 8 + i][x] = make_float2(gx[x], gy[x]);
        }
      }
    }
    __syncthreads();
    if (tid < 80) {
      int ii = tid / 10, q = tid % 10;
      float sx = 0.f, sy = 0.f;
      #pragma unroll
      for (int k = 0; k < 7; ++k) {
        float2 g = Gk[k][ii][q];
        sx += g.x; sy += g.y;
      }
      Gs[lc * 8 + ii][q] = make_float2(sx, sy);
    }
  }
  __syncthreads();

  // solves for this block's l-set: p<3 -> l in {p, p+4} (16); p==3 -> {3} (8)
  int nsol = (p < 3) ? 16 : 8;
  if (tid < 128) {
    int which = tid >> 6;
    int bl = tid & 63;
    if (bl < nsol) {
      int lc = bl >> 3, i2 = bl & 7;
      int l = lc * 4 + p;
      float2 M[NR][NR];
      int ui = 0;
      #pragma unroll
      for (int r = 0; r < 4; ++r)
        #pragma unroll
        for (int s = r; s < 4; ++s) {
          float2 g = Gs[bl][ui];
          if (which) { float2 td = TdL[bl][ui]; g.x -= td.x; g.y -= td.y; }
          ++ui;
          M[r][s] = g;
          M[s][r] = make_float2(g.x, -g.y);
        }
      #pragma unroll
      for (int r = 0; r < 4; ++r) { M[r][r].x += NOISEF; M[r][r].y = 0.f; }
      float2 Bv[NR][DD], X[NR][DD];
      #pragma unroll
      for (int x = 0; x < 8; ++x) Bv[x >> 1][x & 1] = HV2L[bl][x];
      chol_solve(M, Bv, X);
      size_t gb = (size_t)n * 56 + l * 8 + i2;
      if (!which) {
        #pragma unroll
        for (int x = 0; x < 8; ++x) Yb[gb * 8 + x] = X[x >> 1][x & 1];
      } else {
        #pragma unroll
        for (int d = 0; d < DD; ++d)
          #pragma unroll
          for (int e = 0; e < DD; ++e) {
            float gr = (d == e) ? 1.f : 0.f, gi = 0.f;
            #pragma unroll
            for (int r = 0; r < NR; ++r) {
              float2 a = Bv[r][d], x = X[r][e];
              gr += a.x * x.x + a.y * x.y;
              gi += a.x * x.y - a.y * x.x;
            }
            IGb[gb * 4 + d * 2 + e] = make_float2(gr, gi);
          }
      }
    }
  }
}

// ---------------- k_stage2: block per (n,l): A, B=A*IG, L, Lam -> Z2 ----------------
__global__ __launch_bounds__(256) void k_stage2(const float* __restrict__ Hre,
    const float* __restrict__ Him, const float2* __restrict__ Vcur,
    const float2* __restrict__ Yb, const float2* __restrict__ IGb,
    const float* __restrict__ w, float2* __restrict__ Z2out) {
  int nl = blockIdx.x; int l = nl % BS; int n = nl / BS;
  int tid = threadIdx.x;
  __shared__ float2 SM[3686];
  float2* Hsm  = SM;
  float2* Bsm  = SM;
  float2* Lsm  = SM + 952;
  float2* Ysm  = SM + 1792;
  float2* IGsm = SM + 2247;
  float2* Asm  = SM + 2478;
  float2* Lamm = SM + 3430;
  float2* Zlm  = SM + 3558;

  size_t hbase = ((size_t)n * BS + l) * 1792;
  for (int idx = tid; idx < 1792; idx += 256) {
    int t = idx & 7, r = (idx >> 3) & 3, u = (idx >> 5) & 7, m = idx >> 8;
    Hsm[((u * 4 + r) * 7 + m) * 8 + t] = make_float2(Hre[hbase + idx], Him[hbase + idx]);
  }
  const float2* yp = Yb + (size_t)n * 448;
  for (int idx = tid; idx < 448; idx += 256)
    Ysm[(idx >> 6) * 65 + (idx & 63)] = yp[idx];
  const float2* igp = IGb + (size_t)n * 224;
  if (tid < 224) IGsm[(tid >> 5) * 33 + (tid & 31)] = igp[tid];
  const float2* zp = Vcur + (size_t)nl * 128;
  if (tid < 128) Zlm[tid] = zp[tid];
  __syncthreads();

  for (int idx = tid; idx < 896; idx += 256) {
    int u = idx / 112, rem = idx % 112, m = rem >> 4, t = (rem >> 1) & 7, d = rem & 1;
    float ar = 0.f, ai = 0.f;
    #pragma unroll
    for (int r = 0; r < NR; ++r) {
      float2 h = Hsm[((u * 4 + r) * 7 + m) * 8 + t];
      float2 y = Ysm[m * 65 + u * 8 + r * 2 + d];
      ar += h.x * y.x + h.y * y.y;
      ai += h.x * y.y - h.y * y.x;
    }
    Asm[u * 119 + m * 17 + t * 2 + d] = make_float2(ar, ai);
  }
  __syncthreads();

  for (int idx = tid; idx < 896; idx += 256) {
    int u = idx / 112, rem = idx % 112, m = rem >> 4, t = (rem >> 1) & 7, e = rem & 1;
    float br = 0.f, bi = 0.f;
    #pragma unroll
    for (int d = 0; d < DD; ++d) {
      float2 a = Asm[u * 119 + m * 17 + t * 2 + d];
      float2 g = IGsm[m * 33 + u * 4 + d * 2 + e];
      br += a.x * g.x - a.y * g.y;
      bi += a.x * g.y + a.y * g.x;
    }
    Bsm[u * 119 + m * 17 + t * 2 + e] = make_float2(br, bi);
  }
  __syncthreads();

  for (int idx = tid; idx < 512; idx += 256) {
    int u = idx >> 6, t = (idx >> 3) & 7, s = idx & 7;
    float lr = 0.f, li = 0.f;
    #pragma unroll
    for (int m = 0; m < BS; ++m)
      #pragma unroll
      for (int e = 0; e < DD; ++e) {
        float2 bb = Bsm[u * 119 + m * 17 + t * 2 + e];
        float2 ac = Asm[u * 119 + m * 17 + s * 2 + e];
        lr += bb.x * ac.x + bb.y * ac.y;
        li += bb.y * ac.x - bb.x * ac.y;
      }
    float wu = w[u];
    Lsm[(u * 8 + t) * 8 + s] = make_float2(lr * wu, li * wu);
  }
  if (tid < 128) {
    int u = tid >> 4, t = (tid >> 1) & 7, e = tid & 1;
    float ar = 0.f, ai = 0.f;
    #pragma unroll
    for (int d = 0; d < DD; ++d) {
      float2 a = Asm[u * 119 + l * 17 + t * 2 + d];
      float2 g = IGsm[l * 33 + u * 4 + d * 2 + e];
      ar += a.x * g.x - a.y * g.y;
      ai += a.x * g.y + a.y * g.x;
    }
    float wu = w[u];
    Lamm[u * 16 + t * 2 + e] = make_float2(ar * wu, ai * wu);
  }
  __syncthreads();

  if (tid < 128) {
    int u = tid >> 4, t = (tid >> 1) & 7, d = tid & 1;
    float2 lam = Lamm[u * 16 + t * 2 + d];
    float zr = lam.x, zi = lam.y;
    #pragma unroll
    for (int s = 0; s < NT; ++s) {
      float2 Lts = Lsm[(u * 8 + t) * 8 + s];
      float2 z = Zlm[u * 16 + s * 2 + d];
      zr -= Lts.x * z.x - Lts.y * z.y;
      zi -= Lts.x * z.y + Lts.y * z.x;
    }
    Z2out[(size_t)nl * 128 + u * 16 + t * 2 + d] = make_float2(zr, zi);
  }
}

// ---------------- Bpack ----------------
__global__ __launch_bounds__(256) void k_pack(
    const float* __restrict__ W1re, const float* __restrict__ W1im,
    const float* __restrict__ b1re, const float* __restrict__ b1im,
    const float* __restrict__ W2re, const float* __restrict__ W2im,
    const float* __restrict__ b2re, const float* __restrict__ b2im,
    const float* __restrict__ W3re, const float* __restrict__ W3im,
    const float* __restrict__ b3re, const float* __restrict__ b3im,
    _Float16* __restrict__ Bout) {
  int gid = blockIdx.x * 256 + threadIdx.x;
  int lane = gid & 63;
  int rest = gid >> 6;
  int nt = rest % NTILES;
  int id2 = rest / NTILES;
  if (id2 >= 87) return;
  int iter = id2 / 29, kk = id2 % 29;
  int layer, kc;
  if (kk < 3)       { layer = 0; kc = kk; }
  else if (kk < 16) { layer = 1; kc = kk - 3; }
  else              { layer = 2; kc = kk - 16; }
  const float *Wr, *Wi, *br, *bi;
  if (layer == 0) { Wr = W1re + iter*HID*CIN; Wi = W1im + iter*HID*CIN; br = b1re + iter*HID; bi = b1im + iter*HID; }
  else if (layer == 1) { Wr = W2re + iter*HID*HID; Wi = W2im + iter*HID*HID; br = b2re + iter*HID; bi = b2im + iter*HID; }
  else { Wr = W3re + iter*HID*HID; Wi = W3im + iter*HID*HID; br = b3re + iter*HID; bi = b3im + iter*HID; }
  int c = nt * 16 + (lane & 15);
  int o = c >> 1; int odd = c & 1;
  f16x8 frag;
  #pragma unroll
  for (int j = 0; j < 8; ++j) {
    int k = kc * 32 + (lane >> 4) * 8 + j;
    float v = 0.f;
    if (o < HID) {
      if (layer == 0) {
        if (k < 32)       v = odd ? Wi[o*32 + k] : Wr[o*32 + k];
        else if (k < 64)  { int i = k - 32; v = odd ? Wr[o*32 + i] : -Wi[o*32 + i]; }
        else if (k == 64) v = odd ? bi[o] : br[o];
      } else {
        if (k < 200)       v = odd ? Wi[o*200 + k] : Wr[o*200 + k];
        else if (k == 207) v = odd ? bi[o] : br[o];
        else if (k >= 208 && k < 408) { int i = k - 208; v = odd ? Wr[o*200 + i] : -Wi[o*200 + i]; }
      }
    }
    frag[j] = (_Float16)v;
  }
  size_t off = (size_t)iter * BITER_HALVES
             + (layer == 0 ? 0 : (layer == 1 ? B1_HALVES : (B1_HALVES + B23_HALVES)))
             + ((size_t)(kc * NTILES + nt) * 64 + lane) * 8;
  *(f16x8*)(Bout + off) = frag;
}

// ---------------- fused MFMA MLP: 32 rows/block, 8 waves own 3-4 col tiles ----------
template<int ASTRIDE, int KC, int NTL>
__device__ inline void do_gemm(const _Float16* Ain,
                               const _Float16* __restrict__ Bg,
                               _Float16* Aout, int tbase, int lane) {
  f32x4 acc[2][NTL];
  #pragma unroll
  for (int rt = 0; rt < 2; ++rt)
    #pragma unroll
    for (int nt = 0; nt < NTL; ++nt)
      acc[rt][nt] = (f32x4){0.f, 0.f, 0.f, 0.f};
  const int r0 = lane & 15, g = lane >> 4;
  const _Float16* bp0 = Bg + ((size_t)tbase * 64 + lane) * 8;
  const size_t KSTEP = (size_t)NTILES * 512;
  #pragma unroll
  for (int kc = 0; kc < KC; ++kc) {
    f16x8 b[NTL], a[2];
    #pragma unroll
    for (int nt = 0; nt < NTL; ++nt)
      b[nt] = *(const f16x8*)(bp0 + (size_t)kc * KSTEP + nt * 512);
    #pragma unroll
    for (int rt = 0; rt < 2; ++rt)
      a[rt] = *(const f16x8*)(Ain + (r0 + rt * 16) * ASTRIDE + kc * 32 + 8 * g);
    #pragma unroll
    for (int nt = 0; nt < NTL; ++nt)
      #pragma unroll
      for (int rt = 0; rt < 2; ++rt)
        acc[rt][nt] = __builtin_amdgcn_mfma_f32_16x16x32_f16(a[rt], b[nt], acc[rt][nt], 0, 0, 0);
  }
  #pragma unroll
  for (int nt = 0; nt < NTL; ++nt) {
    int c = (tbase + nt) * 16 + r0;
    int o = c >> 1;
    bool isre = !(c & 1);
    if (o < HID) {
      _Float16* outp = Aout + (isre ? o : 208 + o);
      #pragma unroll
      for (int rt = 0; rt < 2; ++rt)
        #pragma unroll
        for (int q = 0; q < 4; ++q) {
          float v = acc[rt][nt][q];
          if (isre) v = fmaxf(v, 0.f);
          outp[(size_t)(rt * 16 + g * 4 + q) * AST] = (_Float16)v;
        }
    }
  }
}

__global__ __launch_bounds__(512, 2) void k_mlp_mfma(
    const float2* __restrict__ Vcur, const float2* __restrict__ Z2,
    const _Float16* __restrict__ Bp,
    const float* __restrict__ W4re, const float* __restrict__ W4im,
    const float* __restrict__ b4re,
    float2* __restrict__ Vout) {
  int b = blockIdx.x;          // owns 32 rows = 4 nl
  int tid = threadIdx.x;
  int wave = tid >> 6, lane = tid & 63;
  int tb = (wave < 4) ? wave * 4 : 16 + (wave - 4) * 3;

  __shared__ _Float16 A0[MROWS * AST0];
  __shared__ _Float16 Abuf[2][MROWS * AST];
  __shared__ float2 Zs[MROWS][16];
  __shared__ float2 Z2s[MROWS][16];
  __shared__ float w4s[2][HID];
  __shared__ float stepv[MROWS];
  __shared__ float scs[4];

  for (int idx = tid; idx < MROWS * 16; idx += 512) {
    ((float2*)Zs)[idx]  = Vcur[(size_t)b * (MROWS * 16) + idx];
    ((float2*)Z2s)[idx] = Z2[(size_t)b * (MROWS * 16) + idx];
  }
  for (int idx = tid; idx < HID; idx += 512) {
    w4s[0][idx] = W4re[idx];
    w4s[1][idx] = W4im[idx];
  }
  __syncthreads();

  for (int idx = tid; idx < MROWS * AST0; idx += 512) {
    int m = idx / AST0, c = idx % AST0;
    float v;
    if (c < 64) {
      int f = c & 31;
      float2 z = (f < 16) ? Zs[m][f] : Z2s[m][f - 16];
      v = (c >= 32) ? z.y : z.x;
    } else v = (c == 64) ? 1.f : 0.f;
    A0[m * AST0 + c] = (_Float16)v;
  }
  for (int idx = tid; idx < 2 * MROWS * 16; idx += 512) {
    int buf = idx >> 9, rem = idx & 511, m = rem >> 4, pp = rem & 15;
    int c = (pp < 8) ? (200 + pp) : (400 + pp);
    Abuf[buf][m * AST + c] = (pp == 7) ? (_Float16)1.f : (_Float16)0.f;
  }
  __syncthreads();

  if (wave < 4) do_gemm<AST0, B1_KC, 4>(A0, Bp, &Abuf[0][0], tb, lane);
  else          do_gemm<AST0, B1_KC, 3>(A0, Bp, &Abuf[0][0], tb, lane);
  __syncthreads();
  if (wave < 4) do_gemm<AST, B23_KC, 4>(&Abuf[0][0], Bp + B1_HALVES, &Abuf[1][0], tb, lane);
  else          do_gemm<AST, B23_KC, 3>(&Abuf[0][0], Bp + B1_HALVES, &Abuf[1][0], tb, lane);
  __syncthreads();
  if (wave < 4) do_gemm<AST, B23_KC, 4>(&Abuf[1][0], Bp + B1_HALVES + B23_HALVES, &Abuf[0][0], tb, lane);
  else          do_gemm<AST, B23_KC, 3>(&Abuf[1][0], Bp + B1_HALVES + B23_HALVES, &Abuf[0][0], tb, lane);
  __syncthreads();

  {  // layer 4: 32 rows x 16 segments
    int m = tid >> 4, q = tid & 15;
    float acc = 0.f;
    for (int o = q; o < HID; o += 16) {
      float hr = (float)Abuf[0][m * AST + o];
      float hi = (float)Abuf[0][m * AST + 208 + o];
      acc += hr * w4s[0][o] - hi * w4s[1][o];
    }
    acc += __shfl_down(acc, 8, 16);
    acc += __shfl_down(acc, 4, 16);
    acc += __shfl_down(acc, 2, 16);
    acc += __shfl_down(acc, 1, 16);
    if (q == 0) stepv[m] = acc + b4re[0];
  }
  __syncthreads();

  {
    int idx = tid;
    int m = idx >> 4, f = idx & 15;
    float st = stepv[m];
    float2 z = Zs[m][f], z2 = Z2s[m][f];
    Zs[m][f] = make_float2(fmaf(st, z2.x, z.x), fmaf(st, z2.y, z.y));
  }
  __syncthreads();

  if (wave < 4) {
    const float2* vp = &Zs[wave * 8][0];
    float2 v0 = vp[lane * 2], v1 = vp[lane * 2 + 1];
    float p = v0.x * v0.x + v0.y * v0.y + v1.x * v1.x + v1.y * v1.y;
    p += __shfl_down(p, 32); p += __shfl_down(p, 16); p += __shfl_down(p, 8);
    p += __shfl_down(p, 4);  p += __shfl_down(p, 2);  p += __shfl_down(p, 1);
    if (lane == 0) scs[wave] = (p > PP) ? sqrtf(PP / p) : 1.f;
  }
  __syncthreads();
  {
    int idx = tid;
    float sc = scs[idx >> 7];
    float2 v = ((float2*)Zs)[idx];
    Vout[(size_t)b * (MROWS * 16) + idx] = make_float2(v.x * sc, v.y * sc);
  }
}

// ---------------- launch ----------------
extern "C" void kernel_launch(void* const* d_in, const int* in_sizes, int n_in,
                              void* d_out, int out_size, void* d_ws, size_t ws_size,
                              hipStream_t stream) {
  const float* Hre  = (const float*)d_in[0];
  const float* Him  = (const float*)d_in[1];
  const float* Vre  = (const float*)d_in[2];
  const float* Vim  = (const float*)d_in[3];
  const float* w    = (const float*)d_in[4];
  const float* W1re = (const float*)d_in[5];
  const float* W1im = (const float*)d_in[6];
  const float* b1re = (const float*)d_in[7];
  const float* b1im = (const float*)d_in[8];
  const float* W2re = (const float*)d_in[9];
  const float* W2im = (const float*)d_in[10];
  const float* b2re = (const float*)d_in[11];
  const float* b2im = (const float*)d_in[12];
  const float* W3re = (const float*)d_in[13];
  const float* W3im = (const float*)d_in[14];
  const float* b3re = (const float*)d_in[15];
  const float* b3im = (const float*)d_in[16];
  const float* W4re = (const float*)d_in[17];
  const float* W4im = (const float*)d_in[18];
  const float* b4re = (const float*)d_in[19];

  const size_t NV = (size_t)NS * BS * UU * NT * DD;   // 229376
  const size_t NB = (size_t)NS * BS * UU;             // 14336
  float2* Vcur = (float2*)d_ws;
  float2* Z2b  = Vcur + NV;
  float2* Yb   = Z2b + NV;
  float2* IGb  = Yb + NB * 8;
  _Float16* Bpack = (_Float16*)(IGb + NB * 4);

  k_pack<<<609, 256, 0, stream>>>(W1re, W1im, b1re, b1im, W2re, W2im, b2re, b2im,
                                  W3re, W3im, b3re, b3im, Bpack);
  k_norm0<<<NS * BS, 128, 0, stream>>>(Vre, Vim, Vcur);
  for (int it = 0; it < 3; ++it) {
    k_s1n<<<NS * 4, 512, 0, stream>>>(Hre, Him, Vcur, Yb, IGb);
    k_stage2<<<NS * BS, 256, 0, stream>>>(Hre, Him, Vcur, Yb, IGb, w, Z2b);
    float2* vout = (it == 2) ? (float2*)d_out : Vcur;
    k_mlp_mfma<<<NS * BS * UU * NT * DD / (MROWS * 16), 512, 0, stream>>>(Vcur, Z2b,
        Bpack + (size_t)it * BITER_HALVES,
        W4re + it * HID, W4im + it * HID, b4re + it, vout);
  }
}

// Round 20
// 212.198 us; speedup vs baseline: 1.0378x; 1.0378x over previous
//
#include <hip/hip_runtime.h>
#include <math.h>

#define NS 256
#define BS 7
#define UU 8
#define NR 4
#define NT 8
#define DD 2
#define HID 200
#define CIN 32
#define PP 100.0f
#define NOISEF 1e-7f

typedef _Float16 f16x8 __attribute__((ext_vector_type(8)));
typedef float f32x4 __attribute__((ext_vector_type(4)));

#define AST 424      // activation buffer row stride (halves)
#define AST0 104     // layer-1 input stride (halves)
#define NTILES 28
#define B1_KC 3
#define B23_KC 13
#define B1_HALVES (B1_KC*NTILES*64*8)
#define B23_HALVES (B23_KC*NTILES*64*8)
#define BITER_HALVES (B1_HALVES + 2*B23_HALVES)
#define MROWS 32     // rows per k_mlp block

// ---------------- 4x4 complex Hermitian PD solve, 2 RHS (Cholesky) ----------------
__device__ void chol_solve(const float2 (*A)[NR], const float2 (*B)[DD], float2 (*X)[DD]) {
  float2 L[NR][NR];
  for (int j = 0; j < NR; ++j) {
    float d = A[j][j].x;
    for (int k = 0; k < j; ++k) d -= L[j][k].x * L[j][k].x + L[j][k].y * L[j][k].y;
    float ld = sqrtf(fmaxf(d, 1e-30f));
    L[j][j] = make_float2(ld, 0.f);
    float inv = 1.f / ld;
    for (int i = j + 1; i < NR; ++i) {
      float sr = A[i][j].x, si = A[i][j].y;
      for (int k = 0; k < j; ++k) {
        float2 a = L[i][k], b = L[j][k];
        sr -= a.x * b.x + a.y * b.y;
        si -= a.y * b.x - a.x * b.y;
      }
      L[i][j] = make_float2(sr * inv, si * inv);
    }
  }
  for (int c = 0; c < DD; ++c) {
    float2 z[NR];
    for (int i = 0; i < NR; ++i) {
      float sr = B[i][c].x, si = B[i][c].y;
      for (int k = 0; k < i; ++k) {
        float2 a = L[i][k], zz = z[k];
        sr -= a.x * zz.x - a.y * zz.y;
        si -= a.x * zz.y + a.y * zz.x;
      }
      float inv = 1.f / L[i][i].x;
      z[i] = make_float2(sr * inv, si * inv);
    }
    for (int i = NR - 1; i >= 0; --i) {
      float sr = z[i].x, si = z[i].y;
      for (int k = i + 1; k < NR; ++k) {
        float2 a = L[k][i], xx = X[k][c];
        sr -= a.x * xx.x + a.y * xx.y;
        si -= a.x * xx.y - a.y * xx.x;
      }
      float inv = 1.f / L[i][i].x;
      X[i][c] = make_float2(sr * inv, si * inv);
    }
  }
}

// ---------------- K0: initial power normalization ----------------
__global__ void k_norm0(const float* __restrict__ Vre, const float* __restrict__ Vim,
                        float2* __restrict__ Vcur) {
  int nl = blockIdx.x;
  int tid = threadIdx.x;
  size_t base = (size_t)nl * 128;
  float re = Vre[base + tid], im = Vim[base + tid];
  float p = re * re + im * im;
  p += __shfl_down(p, 32); p += __shfl_down(p, 16); p += __shfl_down(p, 8);
  p += __shfl_down(p, 4);  p += __shfl_down(p, 2);  p += __shfl_down(p, 1);
  __shared__ float sred[2];
  if ((tid & 63) == 0) sred[tid >> 6] = p;
  __syncthreads();
  float fro = sred[0] + sred[1];
  float sc = sqrtf(PP / fro);
  Vcur[base + tid] = make_float2(re * sc, im * sc);
}

// ---------------- k_s1n v2: 2 blocks per n (l-parity split) -> 2 blocks/CU ----------
// 512 threads = 8 waves. Compute: wave=k, lane=(i,c). Block p handles l = p, p+2, ...
__global__ __launch_bounds__(512, 2) void k_s1n(const float* __restrict__ Hre,
    const float* __restrict__ Him, const float2* __restrict__ Vcur,
    float2* __restrict__ Yb, float2* __restrict__ IGb) {
  int blk = blockIdx.x;
  int p = blk & 1, n = blk >> 1;
  int tid = threadIdx.x;
  int wave = tid >> 6;
  int lane = tid & 63;
  int i = lane >> 3, c = lane & 7;

  __shared__ float2 Vs[952];        // (k*8+j)*17 + t*2+d
  __shared__ float2 Cs[7][76];      // [k] c*9 + t
  __shared__ float2 Hl[7][268];     // [k] i*33 + r*8 + t
  __shared__ float2 Gk[7][8][10];
  __shared__ float2 Gs[32][10];     // [lc*8+i]
  __shared__ float2 TdL[32][10];
  __shared__ float2 HV2L[32][8];

  const float2* Vn = Vcur + (size_t)n * 896;
  for (int idx = tid; idx < 896; idx += 512)
    Vs[(idx >> 4) * 17 + (idx & 15)] = Vn[idx];
  __syncthreads();

  if (tid < 448) {
    int k = tid >> 6, e = tid & 63, cc = e >> 3, t = e & 7;
    float sr = 0.f, si = 0.f;
    #pragma unroll
    for (int j = 0; j < 8; ++j) {
      const float2* vr = &Vs[(k * 8 + j) * 17];
      #pragma unroll
      for (int d = 0; d < 2; ++d) {
        float2 a = vr[t * 2 + d], b = vr[cc * 2 + d];
        sr += a.x * b.x + a.y * b.y;
        si += a.y * b.x - a.x * b.y;
      }
    }
    Cs[k][cc * 9 + t] = make_float2(sr, si);
  }

  for (int l = p; l < BS; l += 2) {
    int lc = l >> 1;
    __syncthreads();
    if (tid < 448) {
      int k = tid >> 6;
      int e4 = (tid & 63) * 4;
      size_t hbase = (((size_t)(n * 7 + k) * 7) + l) * 256 + e4;
      float4 re = *(const float4*)(Hre + hbase);
      float4 im = *(const float4*)(Him + hbase);
      int ii = e4 >> 5, rem = e4 & 31;
      float2* hp = &Hl[k][ii * 33 + rem];
      hp[0] = make_float2(re.x, im.x);
      hp[1] = make_float2(re.y, im.y);
      hp[2] = make_float2(re.z, im.z);
      hp[3] = make_float2(re.w, im.w);
    }
    __syncthreads();

    if (wave < 7) {
      int k = wave;
      const float2* hme = &Hl[k][i * 33];
      const float2* cme = &Cs[k][c * 9];
      float2 T[4];
      #pragma unroll
      for (int r = 0; r < 4; ++r) {
        float tr = 0.f, ti = 0.f;
        #pragma unroll
        for (int t = 0; t < 8; ++t) {
          float2 h = hme[r * 8 + t], cv = cme[t];
          tr += h.x * cv.x - h.y * cv.y;
          ti += h.x * cv.y + h.y * cv.x;
        }
        T[r] = make_float2(tr, ti);
      }
      float2 hb[4];
      #pragma unroll
      for (int s = 0; s < 4; ++s) hb[s] = hme[s * 8 + c];
      float2 G[10];
      {
        int ui = 0;
        #pragma unroll
        for (int r = 0; r < 4; ++r)
          #pragma unroll
          for (int s = r; s < 4; ++s) {
            G[ui].x = T[r].x * hb[s].x + T[r].y * hb[s].y;
            G[ui].y = T[r].y * hb[s].x - T[r].x * hb[s].y;
            ++ui;
          }
      }
      #pragma unroll
      for (int m = 1; m < 8; m <<= 1) {
        #pragma unroll
        for (int q = 0; q < 10; ++q) {
          G[q].x += __shfl_xor(G[q].x, m);
          G[q].y += __shfl_xor(G[q].y, m);
        }
      }
      if (c == 0) {
        #pragma unroll
        for (int q = 0; q < 10; ++q) Gk[k][i][q] = G[q];
      }

      if (k == l) {
        int r = c >> 1, d = c & 1;
        float hvx = 0.f, hvy = 0.f;
        const float2* vp = &Vs[(l * 8 + i) * 17 + d];
        #pragma unroll
        for (int t = 0; t < 8; ++t) {
          float2 h = hme[r * 8 + t], v = vp[t * 2];
          hvx += h.x * v.x - h.y * v.y;
          hvy += h.x * v.y + h.y * v.x;
        }
        float gx[8], gy[8];
        int base = lane & 56;
        #pragma unroll
        for (int pp = 0; pp < 8; ++pp) {
          gx[pp] = __shfl(hvx, base + pp);
          gy[pp] = __shfl(hvy, base + pp);
        }
        if (c == 0) {
          int ui = 0;
          #pragma unroll
          for (int r2 = 0; r2 < 4; ++r2)
            #pragma unroll
            for (int s2 = r2; s2 < 4; ++s2) {
              float tr = 0.f, ti = 0.f;
              #pragma unroll
              for (int d2 = 0; d2 < 2; ++d2) {
                float ax = gx[r2 * 2 + d2], ay = gy[r2 * 2 + d2];
                float bx = gx[s2 * 2 + d2], by = gy[s2 * 2 + d2];
                tr += ax * bx + ay * by;
                ti += ay * bx - ax * by;
              }
              TdL[lc * 8 + i][ui] = make_float2(tr, ti);
              ++ui;
            }
          #pragma unroll
          for (int x = 0; x < 8; ++x)
            HV2L[lc * 8 + i][x] = make_float2(gx[x], gy[x]);
        }
      }
    }
    __syncthreads();
    if (tid < 80) {
      int ii = tid / 10, q = tid % 10;
      float sx = 0.f, sy = 0.f;
      #pragma unroll
      for (int k = 0; k < 7; ++k) {
        float2 g = Gk[k][ii][q];
        sx += g.x; sy += g.y;
      }
      Gs[lc * 8 + ii][q] = make_float2(sx, sy);
    }
  }
  __syncthreads();

  // solves for this block's l-set: p=0 -> 32 (l=0,2,4,6); p=1 -> 24 (l=1,3,5)
  int nsol = (p == 0) ? 32 : 24;
  if (tid < 128) {
    int which = tid >> 6;
    int bl = tid & 63;
    if (bl < nsol) {
      int lc = bl >> 3, i2 = bl & 7;
      int l = lc * 2 + p;
      float2 M[NR][NR];
      int ui = 0;
      #pragma unroll
      for (int r = 0; r < 4; ++r)
        #pragma unroll
        for (int s = r; s < 4; ++s) {
          float2 g = Gs[bl][ui];
          if (which) { float2 td = TdL[bl][ui]; g.x -= td.x; g.y -= td.y; }
          ++ui;
          M[r][s] = g;
          M[s][r] = make_float2(g.x, -g.y);
        }
      #pragma unroll
      for (int r = 0; r < 4; ++r) { M[r][r].x += NOISEF; M[r][r].y = 0.f; }
      float2 Bv[NR][DD], X[NR][DD];
      #pragma unroll
      for (int x = 0; x < 8; ++x) Bv[x >> 1][x & 1] = HV2L[bl][x];
      chol_solve(M, Bv, X);
      size_t gb = (size_t)n * 56 + l * 8 + i2;
      if (!which) {
        #pragma unroll
        for (int x = 0; x < 8; ++x) Yb[gb * 8 + x] = X[x >> 1][x & 1];
      } else {
        #pragma unroll
        for (int d = 0; d < DD; ++d)
          #pragma unroll
          for (int e = 0; e < DD; ++e) {
            float gr = (d == e) ? 1.f : 0.f, gi = 0.f;
            #pragma unroll
            for (int r = 0; r < NR; ++r) {
              float2 a = Bv[r][d], x = X[r][e];
              gr += a.x * x.x + a.y * x.y;
              gi += a.x * x.y - a.y * x.x;
            }
            IGb[gb * 4 + d * 2 + e] = make_float2(gr, gi);
          }
      }
    }
  }
}

// ---------------- k_stage2: block per (n,l): A, B=A*IG, L, Lam -> Z2 ----------------
__global__ __launch_bounds__(256) void k_stage2(const float* __restrict__ Hre,
    const float* __restrict__ Him, const float2* __restrict__ Vcur,
    const float2* __restrict__ Yb, const float2* __restrict__ IGb,
    const float* __restrict__ w, float2* __restrict__ Z2out) {
  int nl = blockIdx.x; int l = nl % BS; int n = nl / BS;
  int tid = threadIdx.x;
  __shared__ float2 SM[3686];
  float2* Hsm  = SM;
  float2* Bsm  = SM;
  float2* Lsm  = SM + 952;
  float2* Ysm  = SM + 1792;
  float2* IGsm = SM + 2247;
  float2* Asm  = SM + 2478;
  float2* Lamm = SM + 3430;
  float2* Zlm  = SM + 3558;

  size_t hbase = ((size_t)n * BS + l) * 1792;
  for (int idx = tid; idx < 1792; idx += 256) {
    int t = idx & 7, r = (idx >> 3) & 3, u = (idx >> 5) & 7, m = idx >> 8;
    Hsm[((u * 4 + r) * 7 + m) * 8 + t] = make_float2(Hre[hbase + idx], Him[hbase + idx]);
  }
  const float2* yp = Yb + (size_t)n * 448;
  for (int idx = tid; idx < 448; idx += 256)
    Ysm[(idx >> 6) * 65 + (idx & 63)] = yp[idx];
  const float2* igp = IGb + (size_t)n * 224;
  if (tid < 224) IGsm[(tid >> 5) * 33 + (tid & 31)] = igp[tid];
  const float2* zp = Vcur + (size_t)nl * 128;
  if (tid < 128) Zlm[tid] = zp[tid];
  __syncthreads();

  for (int idx = tid; idx < 896; idx += 256) {
    int u = idx / 112, rem = idx % 112, m = rem >> 4, t = (rem >> 1) & 7, d = rem & 1;
    float ar = 0.f, ai = 0.f;
    #pragma unroll
    for (int r = 0; r < NR; ++r) {
      float2 h = Hsm[((u * 4 + r) * 7 + m) * 8 + t];
      float2 y = Ysm[m * 65 + u * 8 + r * 2 + d];
      ar += h.x * y.x + h.y * y.y;
      ai += h.x * y.y - h.y * y.x;
    }
    Asm[u * 119 + m * 17 + t * 2 + d] = make_float2(ar, ai);
  }
  __syncthreads();

  for (int idx = tid; idx < 896; idx += 256) {
    int u = idx / 112, rem = idx % 112, m = rem >> 4, t = (rem >> 1) & 7, e = rem & 1;
    float br = 0.f, bi = 0.f;
    #pragma unroll
    for (int d = 0; d < DD; ++d) {
      float2 a = Asm[u * 119 + m * 17 + t * 2 + d];
      float2 g = IGsm[m * 33 + u * 4 + d * 2 + e];
      br += a.x * g.x - a.y * g.y;
      bi += a.x * g.y + a.y * g.x;
    }
    Bsm[u * 119 + m * 17 + t * 2 + e] = make_float2(br, bi);
  }
  __syncthreads();

  for (int idx = tid; idx < 512; idx += 256) {
    int u = idx >> 6, t = (idx >> 3) & 7, s = idx & 7;
    float lr = 0.f, li = 0.f;
    #pragma unroll
    for (int m = 0; m < BS; ++m)
      #pragma unroll
      for (int e = 0; e < DD; ++e) {
        float2 bb = Bsm[u * 119 + m * 17 + t * 2 + e];
        float2 ac = Asm[u * 119 + m * 17 + s * 2 + e];
        lr += bb.x * ac.x + bb.y * ac.y;
        li += bb.y * ac.x - bb.x * ac.y;
      }
    float wu = w[u];
    Lsm[(u * 8 + t) * 8 + s] = make_float2(lr * wu, li * wu);
  }
  if (tid < 128) {
    int u = tid >> 4, t = (tid >> 1) & 7, e = tid & 1;
    float ar = 0.f, ai = 0.f;
    #pragma unroll
    for (int d = 0; d < DD; ++d) {
      float2 a = Asm[u * 119 + l * 17 + t * 2 + d];
      float2 g = IGsm[l * 33 + u * 4 + d * 2 + e];
      ar += a.x * g.x - a.y * g.y;
      ai += a.x * g.y + a.y * g.x;
    }
    float wu = w[u];
    Lamm[u * 16 + t * 2 + e] = make_float2(ar * wu, ai * wu);
  }
  __syncthreads();

  if (tid < 128) {
    int u = tid >> 4, t = (tid >> 1) & 7, d = tid & 1;
    float2 lam = Lamm[u * 16 + t * 2 + d];
    float zr = lam.x, zi = lam.y;
    #pragma unroll
    for (int s = 0; s < NT; ++s) {
      float2 Lts = Lsm[(u * 8 + t) * 8 + s];
      float2 z = Zlm[u * 16 + s * 2 + d];
      zr -= Lts.x * z.x - Lts.y * z.y;
      zi -= Lts.x * z.y + Lts.y * z.x;
    }
    Z2out[(size_t)nl * 128 + u * 16 + t * 2 + d] = make_float2(zr, zi);
  }
}

// ---------------- Bpack ----------------
__global__ __launch_bounds__(256) void k_pack(
    const float* __restrict__ W1re, const float* __restrict__ W1im,
    const float* __restrict__ b1re, const float* __restrict__ b1im,
    const float* __restrict__ W2re, const float* __restrict__ W2im,
    const float* __restrict__ b2re, const float* __restrict__ b2im,
    const float* __restrict__ W3re, const float* __restrict__ W3im,
    const float* __restrict__ b3re, const float* __restrict__ b3im,
    _Float16* __restrict__ Bout) {
  int gid = blockIdx.x * 256 + threadIdx.x;
  int lane = gid & 63;
  int rest = gid >> 6;
  int nt = rest % NTILES;
  int id2 = rest / NTILES;
  if (id2 >= 87) return;
  int iter = id2 / 29, kk = id2 % 29;
  int layer, kc;
  if (kk < 3)       { layer = 0; kc = kk; }
  else if (kk < 16) { layer = 1; kc = kk - 3; }
  else              { layer = 2; kc = kk - 16; }
  const float *Wr, *Wi, *br, *bi;
  if (layer == 0) { Wr = W1re + iter*HID*CIN; Wi = W1im + iter*HID*CIN; br = b1re + iter*HID; bi = b1im + iter*HID; }
  else if (layer == 1) { Wr = W2re + iter*HID*HID; Wi = W2im + iter*HID*HID; br = b2re + iter*HID; bi = b2im + iter*HID; }
  else { Wr = W3re + iter*HID*HID; Wi = W3im + iter*HID*HID; br = b3re + iter*HID; bi = b3im + iter*HID; }
  int c = nt * 16 + (lane & 15);
  int o = c >> 1; int odd = c & 1;
  f16x8 frag;
  #pragma unroll
  for (int j = 0; j < 8; ++j) {
    int k = kc * 32 + (lane >> 4) * 8 + j;
    float v = 0.f;
    if (o < HID) {
      if (layer == 0) {
        if (k < 32)       v = odd ? Wi[o*32 + k] : Wr[o*32 + k];
        else if (k < 64)  { int i = k - 32; v = odd ? Wr[o*32 + i] : -Wi[o*32 + i]; }
        else if (k == 64) v = odd ? bi[o] : br[o];
      } else {
        if (k < 200)       v = odd ? Wi[o*200 + k] : Wr[o*200 + k];
        else if (k == 207) v = odd ? bi[o] : br[o];
        else if (k >= 208 && k < 408) { int i = k - 208; v = odd ? Wr[o*200 + i] : -Wi[o*200 + i]; }
      }
    }
    frag[j] = (_Float16)v;
  }
  size_t off = (size_t)iter * BITER_HALVES
             + (layer == 0 ? 0 : (layer == 1 ? B1_HALVES : (B1_HALVES + B23_HALVES)))
             + ((size_t)(kc * NTILES + nt) * 64 + lane) * 8;
  *(f16x8*)(Bout + off) = frag;
}

// ---------------- fused MFMA MLP: 32 rows/block, 8 waves own 3-4 col tiles ----------
template<int ASTRIDE, int KC, int NTL>
__device__ inline void do_gemm(const _Float16* Ain,
                               const _Float16* __restrict__ Bg,
                               _Float16* Aout, int tbase, int lane) {
  f32x4 acc[2][NTL];
  #pragma unroll
  for (int rt = 0; rt < 2; ++rt)
    #pragma unroll
    for (int nt = 0; nt < NTL; ++nt)
      acc[rt][nt] = (f32x4){0.f, 0.f, 0.f, 0.f};
  const int r0 = lane & 15, g = lane >> 4;
  const _Float16* bp0 = Bg + ((size_t)tbase * 64 + lane) * 8;
  const size_t KSTEP = (size_t)NTILES * 512;
  #pragma unroll
  for (int kc = 0; kc < KC; ++kc) {
    f16x8 b[NTL], a[2];
    #pragma unroll
    for (int nt = 0; nt < NTL; ++nt)
      b[nt] = *(const f16x8*)(bp0 + (size_t)kc * KSTEP + nt * 512);
    #pragma unroll
    for (int rt = 0; rt < 2; ++rt)
      a[rt] = *(const f16x8*)(Ain + (r0 + rt * 16) * ASTRIDE + kc * 32 + 8 * g);
    #pragma unroll
    for (int nt = 0; nt < NTL; ++nt)
      #pragma unroll
      for (int rt = 0; rt < 2; ++rt)
        acc[rt][nt] = __builtin_amdgcn_mfma_f32_16x16x32_f16(a[rt], b[nt], acc[rt][nt], 0, 0, 0);
  }
  #pragma unroll
  for (int nt = 0; nt < NTL; ++nt) {
    int c = (tbase + nt) * 16 + r0;
    int o = c >> 1;
    bool isre = !(c & 1);
    if (o < HID) {
      _Float16* outp = Aout + (isre ? o : 208 + o);
      #pragma unroll
      for (int rt = 0; rt < 2; ++rt)
        #pragma unroll
        for (int q = 0; q < 4; ++q) {
          float v = acc[rt][nt][q];
          if (isre) v = fmaxf(v, 0.f);
          outp[(size_t)(rt * 16 + g * 4 + q) * AST] = (_Float16)v;
        }
    }
  }
}

__global__ __launch_bounds__(512, 2) void k_mlp_mfma(
    const float2* __restrict__ Vcur, const float2* __restrict__ Z2,
    const _Float16* __restrict__ Bp,
    const float* __restrict__ W4re, const float* __restrict__ W4im,
    const float* __restrict__ b4re,
    float2* __restrict__ Vout) {
  int b = blockIdx.x;          // owns 32 rows = 4 nl
  int tid = threadIdx.x;
  int wave = tid >> 6, lane = tid & 63;
  int tb = (wave < 4) ? wave * 4 : 16 + (wave - 4) * 3;

  __shared__ _Float16 A0[MROWS * AST0];
  __shared__ _Float16 Abuf[2][MROWS * AST];
  __shared__ float2 Zs[MROWS][16];
  __shared__ float2 Z2s[MROWS][16];
  __shared__ float w4s[2][HID];
  __shared__ float stepv[MROWS];
  __shared__ float scs[4];

  for (int idx = tid; idx < MROWS * 16; idx += 512) {
    ((float2*)Zs)[idx]  = Vcur[(size_t)b * (MROWS * 16) + idx];
    ((float2*)Z2s)[idx] = Z2[(size_t)b * (MROWS * 16) + idx];
  }
  for (int idx = tid; idx < HID; idx += 512) {
    w4s[0][idx] = W4re[idx];
    w4s[1][idx] = W4im[idx];
  }
  __syncthreads();

  for (int idx = tid; idx < MROWS * AST0; idx += 512) {
    int m = idx / AST0, c = idx % AST0;
    float v;
    if (c < 64) {
      int f = c & 31;
      float2 z = (f < 16) ? Zs[m][f] : Z2s[m][f - 16];
      v = (c >= 32) ? z.y : z.x;
    } else v = (c == 64) ? 1.f : 0.f;
    A0[m * AST0 + c] = (_Float16)v;
  }
  for (int idx = tid; idx < 2 * MROWS * 16; idx += 512) {
    int buf = idx >> 9, rem = idx & 511, m = rem >> 4, pp = rem & 15;
    int c = (pp < 8) ? (200 + pp) : (400 + pp);
    Abuf[buf][m * AST + c] = (pp == 7) ? (_Float16)1.f : (_Float16)0.f;
  }
  __syncthreads();

  if (wave < 4) do_gemm<AST0, B1_KC, 4>(A0, Bp, &Abuf[0][0], tb, lane);
  else          do_gemm<AST0, B1_KC, 3>(A0, Bp, &Abuf[0][0], tb, lane);
  __syncthreads();
  if (wave < 4) do_gemm<AST, B23_KC, 4>(&Abuf[0][0], Bp + B1_HALVES, &Abuf[1][0], tb, lane);
  else          do_gemm<AST, B23_KC, 3>(&Abuf[0][0], Bp + B1_HALVES, &Abuf[1][0], tb, lane);
  __syncthreads();
  if (wave < 4) do_gemm<AST, B23_KC, 4>(&Abuf[1][0], Bp + B1_HALVES + B23_HALVES, &Abuf[0][0], tb, lane);
  else          do_gemm<AST, B23_KC, 3>(&Abuf[1][0], Bp + B1_HALVES + B23_HALVES, &Abuf[0][0], tb, lane);
  __syncthreads();

  {  // layer 4: 32 rows x 16 segments
    int m = tid >> 4, q = tid & 15;
    float acc = 0.f;
    for (int o = q; o < HID; o += 16) {
      float hr = (float)Abuf[0][m * AST + o];
      float hi = (float)Abuf[0][m * AST + 208 + o];
      acc += hr * w4s[0][o] - hi * w4s[1][o];
    }
    acc += __shfl_down(acc, 8, 16);
    acc += __shfl_down(acc, 4, 16);
    acc += __shfl_down(acc, 2, 16);
    acc += __shfl_down(acc, 1, 16);
    if (q == 0) stepv[m] = acc + b4re[0];
  }
  __syncthreads();

  {
    int idx = tid;
    int m = idx >> 4, f = idx & 15;
    float st = stepv[m];
    float2 z = Zs[m][f], z2 = Z2s[m][f];
    Zs[m][f] = make_float2(fmaf(st, z2.x, z.x), fmaf(st, z2.y, z.y));
  }
  __syncthreads();

  if (wave < 4) {
    const float2* vp = &Zs[wave * 8][0];
    float2 v0 = vp[lane * 2], v1 = vp[lane * 2 + 1];
    float p = v0.x * v0.x + v0.y * v0.y + v1.x * v1.x + v1.y * v1.y;
    p += __shfl_down(p, 32); p += __shfl_down(p, 16); p += __shfl_down(p, 8);
    p += __shfl_down(p, 4);  p += __shfl_down(p, 2);  p += __shfl_down(p, 1);
    if (lane == 0) scs[wave] = (p > PP) ? sqrtf(PP / p) : 1.f;
  }
  __syncthreads();
  {
    int idx = tid;
    float sc = scs[idx >> 7];
    float2 v = ((float2*)Zs)[idx];
    Vout[(size_t)b * (MROWS * 16) + idx] = make_float2(v.x * sc, v.y * sc);
  }
}

// ---------------- launch ----------------
extern "C" void kernel_launch(void* const* d_in, const int* in_sizes, int n_in,
                              void* d_out, int out_size, void* d_ws, size_t ws_size,
                              hipStream_t stream) {
  const float* Hre  = (const float*)d_in[0];
  const float* Him  = (const float*)d_in[1];
  const float* Vre  = (const float*)d_in[2];
  const float* Vim  = (const float*)d_in[3];
  const float* w    = (const float*)d_in[4];
  const float* W1re = (const float*)d_in[5];
  const float* W1im = (const float*)d_in[6];
  const float* b1re = (const float*)d_in[7];
  const float* b1im = (const float*)d_in[8];
  const float* W2re = (const float*)d_in[9];
  const float* W2im = (const float*)d_in[10];
  const float* b2re = (const float*)d_in[11];
  const float* b2im = (const float*)d_in[12];
  const float* W3re = (const float*)d_in[13];
  const float* W3im = (const float*)d_in[14];
  const float* b3re = (const float*)d_in[15];
  const float* b3im = (const float*)d_in[16];
  const float* W4re = (const float*)d_in[17];
  const float* W4im = (const float*)d_in[18];
  const float* b4re = (const float*)d_in[19];

  const size_t NV = (size_t)NS * BS * UU * NT * DD;   // 229376
  const size_t NB = (size_t)NS * BS * UU;             // 14336
  float2* Vcur = (float2*)d_ws;
  float2* Z2b  = Vcur + NV;
  float2* Yb   = Z2b + NV;
  float2* IGb  = Yb + NB * 8;
  _Float16* Bpack = (_Float16*)(IGb + NB * 4);

  k_pack<<<609, 256, 0, stream>>>(W1re, W1im, b1re, b1im, W2re, W2im, b2re, b2im,
                                  W3re, W3im, b3re, b3im, Bpack);
  k_norm0<<<NS * BS, 128, 0, stream>>>(Vre, Vim, Vcur);
  for (int it = 0; it < 3; ++it) {
    k_s1n<<<NS * 2, 512, 0, stream>>>(Hre, Him, Vcur, Yb, IGb);
    k_stage2<<<NS * BS, 256, 0, stream>>>(Hre, Him, Vcur, Yb, IGb, w, Z2b);
    float2* vout = (it == 2) ? (float2*)d_out : Vcur;
    k_mlp_mfma<<<NS * BS * UU * NT * DD / (MROWS * 16), 512, 0, stream>>>(Vcur, Z2b,
        Bpack + (size_t)it * BITER_HALVES,
        W4re + it * HID, W4im + it * HID, b4re + it, vout);
  }
}